// Round 11
// baseline (124.353 us; speedup 1.0000x reference)
//
#include <hip/hip_runtime.h>

#define NEG_INF (-10000.0f)
#define L_SEQ   100
#define N_COLS  6464      // BS*(L+1)
#define D_      64
#define N_ROWS  6400      // BS*L
#define NS      16        // column splits
#define NGRP    50        // row groups (128 rows each)

// ws byte offsets
#define OFF_PS  0         // float[6400*16] = 409600
#define OFF_XT  409600    // float[6400]    =  25600
#define OFF_CTL 435200    // float acc[2] | u32 done | u32 rowcnt[50] = 212 B

typedef __attribute__((ext_vector_type(8))) short short8;
typedef __attribute__((ext_vector_type(4))) float f32x4;
union F8 { short8 v; unsigned short u[8]; unsigned w[4]; };

__device__ __forceinline__ unsigned short f2bf(float f) {  // RTN
  unsigned u = __float_as_uint(f);
  return (unsigned short)((u + 0x7FFFu + ((u >> 16) & 1u)) >> 16);
}
__device__ __forceinline__ unsigned packbf(float lo, float hi) {  // trunc pack
  return (__float_as_uint(hi) & 0xFFFF0000u) | (__float_as_uint(lo) >> 16);
}

// grid (50, 16), 256 threads = 4 waves; block owns 128 ROWS x 1/16 of columns.
// Body identical to R10. NEW: merge is folded in via hierarchical tickets —
// the 16th finisher of each row-group merges its 128 rows (8 KB) and the
// 50th group-finisher writes the final mean. ONE worker kernel total.
__global__ __launch_bounds__(256, 2) void fused_kernel(
    const float* __restrict__ prec, const float* __restrict__ score,
    const float* __restrict__ pop, const int* __restrict__ sid,
    const int* __restrict__ lm,
    float* __restrict__ ps, float* __restrict__ xtrow,
    float* __restrict__ acc, unsigned* __restrict__ done,
    unsigned* __restrict__ rowcnt, float* __restrict__ out) {
  __shared__ unsigned bs[3][512];           // 3 hashed bitsets, 16384 bits each
  __shared__ unsigned short btile[64 * 64]; // B supertile, bf16, XOR-swizzled
  __shared__ float mdl[3 * 64];             // mask/pop factor per (seq-slot, col)
  __shared__ float red[8];
  __shared__ unsigned ticket_s;

  const int tid = threadIdx.x;
  const int split = blockIdx.y;
  const int blkrow = blockIdx.x * 128;
  const int w = tid >> 6, lane = tid & 63;
  const int lr = lane & 15, lk = lane >> 4;
  const int i0 = blkrow / L_SEQ;

  // per-wave row groups: rg=0 -> blkrow + w*16, rg=1 -> +64
  int rowbase[2], rbase4[2], sel_a[2], sel_b[2], lim[2];
#pragma unroll
  for (int rg = 0; rg < 2; ++rg) {
    rowbase[rg] = blkrow + rg * 64 + w * 16;
    rbase4[rg] = rowbase[rg] + lk * 4;
    int ia = rbase4[rg] / L_SEQ, ib = (rbase4[rg] + 3) / L_SEQ;
    sel_a[rg] = ia - i0;
    sel_b[rg] = ib - i0;
    lim[rg] = (ia + 1) * L_SEQ;
  }

  // ---- build hashed dup bitsets for the (up to) 3 sequences ----
  for (int x = tid; x < 3 * 512; x += 256) ((unsigned*)bs)[x] = 0u;
  __syncthreads();
  for (int x = tid; x < 303; x += 256) {
    int s = x / 101, pos = x - s * 101;
    int iq = i0 + s; if (iq > 63) iq = 63;
    int id = sid[iq * 101 + pos];
    atomicOr(&bs[s][(id >> 5) & 511], 1u << (id & 31));
  }

  // ---- A fragments: two row groups (f32 -> bf16 RTN) ----
  F8 fa[2][2];
#pragma unroll
  for (int rg = 0; rg < 2; ++rg) {
    const float* prow = prec + (size_t)(rowbase[rg] + lr) * D_ + lk * 8;
    float4 a0 = *(const float4*)(prow);
    float4 a1 = *(const float4*)(prow + 4);
    float4 b0 = *(const float4*)(prow + 32);
    float4 b1 = *(const float4*)(prow + 36);
    fa[rg][0].u[0] = f2bf(a0.x); fa[rg][0].u[1] = f2bf(a0.y);
    fa[rg][0].u[2] = f2bf(a0.z); fa[rg][0].u[3] = f2bf(a0.w);
    fa[rg][0].u[4] = f2bf(a1.x); fa[rg][0].u[5] = f2bf(a1.y);
    fa[rg][0].u[6] = f2bf(a1.z); fa[rg][0].u[7] = f2bf(a1.w);
    fa[rg][1].u[0] = f2bf(b0.x); fa[rg][1].u[1] = f2bf(b0.y);
    fa[rg][1].u[2] = f2bf(b0.z); fa[rg][1].u[3] = f2bf(b0.w);
    fa[rg][1].u[4] = f2bf(b1.x); fa[rg][1].u[5] = f2bf(b1.y);
    fa[rg][1].u[6] = f2bf(b1.z); fa[rg][1].u[7] = f2bf(b1.w);
  }

  float s[2][4][4];
#pragma unroll
  for (int rg = 0; rg < 2; ++rg)
#pragma unroll
    for (int t4 = 0; t4 < 4; ++t4)
#pragma unroll
      for (int q = 0; q < 4; ++q) s[rg][t4][q] = 0.f;

  // staging registers (tile t+1 in flight during compute of t)
  float4 sv[4];
  int svN = 0, lmvN = 0;

  auto STAGE_ISSUE = [&](int stv) {
    const float* base = score + (size_t)stv * 64 * D_;
#pragma unroll
    for (int j = 0; j < 4; ++j)
      sv[j] = *(const float4*)(base + j * 1024 + tid * 4);
    if (tid < 64) {
      int c = stv * 64 + tid;
      svN = sid[c];
      int i2 = c / 101, p = c - i2 * 101;
      lmvN = (p == L_SEQ) ? 1 : lm[i2 * L_SEQ + p];
    }
  };
  auto STAGE_WRITE = [&]() {
#pragma unroll
    for (int j = 0; j < 4; ++j) {
      int colw = j * 16 + (tid >> 4);
      int byteoff = colw * 128 + ((((tid & 15) * 8)) ^ ((colw & 7) << 4));
      uint2 pk;
      pk.x = packbf(sv[j].x, sv[j].y);
      pk.y = packbf(sv[j].z, sv[j].w);
      *(uint2*)((char*)btile + byteoff) = pk;
    }
    if (tid < 64) {
      float inv = 1.0f / pop[svN];
      unsigned hb = 1u << (svN & 31);
      int hw = (svN >> 5) & 511;
      mdl[tid]       = (lmvN && !(bs[0][hw] & hb)) ? inv : 0.f;
      mdl[64 + tid]  = (lmvN && !(bs[1][hw] & hb)) ? inv : 0.f;
      mdl[128 + tid] = (lmvN && !(bs[2][hw] & hb)) ? inv : 0.f;
    }
  };
  auto COMPUTE = [&]() {
    const int sw = (lr & 7) << 4;
    F8 fb0[4], fb1[4];
#pragma unroll
    for (int t4 = 0; t4 < 4; ++t4) {
      int col = t4 * 16 + lr;
      char* rowp = (char*)btile + col * 128;
      fb0[t4].v = *(const short8*)(rowp + ((lk * 16) ^ sw));
      fb1[t4].v = *(const short8*)(rowp + ((64 + lk * 16) ^ sw));
    }
#pragma unroll
    for (int rg = 0; rg < 2; ++rg) {
      float ma[4], mb[4];
#pragma unroll
      for (int t4 = 0; t4 < 4; ++t4) {
        ma[t4] = mdl[sel_a[rg] * 64 + t4 * 16 + lr];
        mb[t4] = mdl[sel_b[rg] * 64 + t4 * 16 + lr];
      }
      f32x4 acc4[4];
#pragma unroll
      for (int t4 = 0; t4 < 4; ++t4) {
        f32x4 z = {0.f, 0.f, 0.f, 0.f};
        z = __builtin_amdgcn_mfma_f32_16x16x32_bf16(fa[rg][0].v, fb0[t4].v, z, 0, 0, 0);
        z = __builtin_amdgcn_mfma_f32_16x16x32_bf16(fa[rg][1].v, fb1[t4].v, z, 0, 0, 0);
        acc4[t4] = z;
      }
#pragma unroll
      for (int q = 0; q < 4; ++q) {
        const bool ub = (rbase4[rg] + q) >= lim[rg];
#pragma unroll
        for (int t4 = 0; t4 < 4; ++t4) {
          float mm = ub ? mb[t4] : ma[t4];
          s[rg][t4][q] = fmaf(__expf(acc4[t4][q]), mm, s[rg][t4][q]);
        }
      }
    }
  };

  // ---- main loop over this split's supertiles (champion skeleton) ----
  const int nit = (100 - split) / NS + 1;  // 6 or 7
  int st = split;
  STAGE_ISSUE(st);
  __syncthreads();       // bitsets ready (STAGE_WRITE reads them)
  STAGE_WRITE();
  __syncthreads();       // tile 0 ready
  for (int t = 0; t < nit; ++t) {
    const bool more = (t + 1 < nit);
    if (more) STAGE_ISSUE(st + NS);
    COMPUTE();
    if (more) {
      __syncthreads();   // all waves done reading LDS tile t
      STAGE_WRITE();
      __syncthreads();   // tile t+1 ready
    }
    st += NS;
  }

  // ---- reduce across the 16 col-lanes per row; store partials ----
#pragma unroll
  for (int rg = 0; rg < 2; ++rg) {
    float sq[4];
#pragma unroll
    for (int q = 0; q < 4; ++q)
      sq[q] = (s[rg][0][q] + s[rg][1][q]) + (s[rg][2][q] + s[rg][3][q]);
#pragma unroll
    for (int q = 0; q < 4; ++q) {
#pragma unroll
      for (int off = 1; off < 16; off <<= 1)
        sq[q] += __shfl_xor(sq[q], off);
    }
    if (lr == 0) {
#pragma unroll
      for (int q = 0; q < 4; ++q)
        ps[(size_t)(rbase4[rg] + q) * NS + split] = sq[q];
    }
  }

  // ---- target logits: one extra MFMA per row group (split 0 only) ----
  if (split == 0) {
#pragma unroll
    for (int rg = 0; rg < 2; ++rg) {
      int row_l = rowbase[rg] + lr;
      int i_l = row_l / L_SEQ, j_l = row_l - i_l * L_SEQ;
      int tgtc = i_l * 101 + j_l + 1;
      int p_l = j_l + 1;
      int vt = (p_l == L_SEQ) ? 1 : lm[i_l * L_SEQ + p_l];
      const float* srp = score + (size_t)tgtc * D_ + lk * 8;
      float4 s0 = *(const float4*)(srp);
      float4 s1 = *(const float4*)(srp + 4);
      float4 s2 = *(const float4*)(srp + 32);
      float4 s3 = *(const float4*)(srp + 36);
      F8 ft0, ft1;
      ft0.w[0] = packbf(s0.x, s0.y); ft0.w[1] = packbf(s0.z, s0.w);
      ft0.w[2] = packbf(s1.x, s1.y); ft0.w[3] = packbf(s1.z, s1.w);
      ft1.w[0] = packbf(s2.x, s2.y); ft1.w[1] = packbf(s2.z, s2.w);
      ft1.w[2] = packbf(s3.x, s3.y); ft1.w[3] = packbf(s3.z, s3.w);
      f32x4 z = {0.f, 0.f, 0.f, 0.f};
      z = __builtin_amdgcn_mfma_f32_16x16x32_bf16(fa[rg][0].v, ft0.v, z, 0, 0, 0);
      z = __builtin_amdgcn_mfma_f32_16x16x32_bf16(fa[rg][1].v, ft1.v, z, 0, 0, 0);
      int qs = lr - lk * 4;   // diagonal: C[row][col] with row=lk*4+q, col=lr
      if (qs >= 0 && qs < 4) {
        float zd = (qs == 0) ? z[0] : (qs == 1) ? z[1] : (qs == 2) ? z[2] : z[3];
        float xv = zd - __logf(pop[sid[tgtc]]);
        xtrow[row_l] = vt ? xv : NEG_INF;
      }
    }
  }

  // ---- hierarchical ticket merge (replaces the separate merge kernel) ----
  __threadfence();                       // release: ps/xt stores visible
  if (tid == 0) ticket_s = atomicAdd(&rowcnt[blockIdx.x], 1u);
  __syncthreads();
  if (ticket_s == NS - 1) {              // last split of this row-group
    __threadfence();                     // acquire: see all 16 splits' ps
    float lsum = 0.f, lcnt = 0.f;
    if (tid < 128) {
      int r = blkrow + tid;
      const float4* pp = (const float4*)(ps + (size_t)r * NS);
      float4 a = pp[0], b = pp[1], c = pp[2], d = pp[3];
      float sv2 = ((a.x + a.y) + (a.z + a.w)) + ((b.x + b.y) + (b.z + b.w)) +
                  ((c.x + c.y) + (c.z + c.w)) + ((d.x + d.y) + (d.z + d.w));
      float x = xtrow[r];
      sv2 += __expf(x);                  // exp(NEG_INF)==0 if target col invalid
      sv2 = fmaxf(sv2, 1e-37f);
      if (lm[r] != 0) { lsum = __logf(sv2) - x; lcnt = 1.f; }
    }
#pragma unroll
    for (int off = 1; off < 64; off <<= 1) {
      lsum += __shfl_xor(lsum, off);
      lcnt += __shfl_xor(lcnt, off);
    }
    if (lane == 0) { red[w] = lsum; red[4 + w] = lcnt; }
    __syncthreads();
    if (tid == 0) {
      float bsum = (red[0] + red[1]) + (red[2] + red[3]);
      float bcnt = (red[4] + red[5]) + (red[6] + red[7]);
      atomicAdd(&acc[0], bsum);
      atomicAdd(&acc[1], bcnt);
      __threadfence();
      unsigned t = atomicAdd(done, 1u);
      if (t == NGRP - 1) {
        float S = atomicAdd(&acc[0], 0.f);
        float C = atomicAdd(&acc[1], 0.f);
        out[0] = S / C;
      }
    }
  }
}

extern "C" void kernel_launch(void* const* d_in, const int* in_sizes, int n_in,
                              void* d_out, int out_size, void* d_ws, size_t ws_size,
                              hipStream_t stream) {
  const float* prec  = (const float*)d_in[0];
  const float* score = (const float*)d_in[1];
  const float* pop   = (const float*)d_in[2];
  const int*   sid   = (const int*)d_in[3];
  const int*   lm    = (const int*)d_in[4];

  char* ws = (char*)d_ws;
  float*    ps     = (float*)(ws + OFF_PS);
  float*    xtrow  = (float*)(ws + OFF_XT);
  float*    acc    = (float*)(ws + OFF_CTL);
  unsigned* done   = (unsigned*)(ws + OFF_CTL + 8);
  unsigned* rowcnt = (unsigned*)(ws + OFF_CTL + 12);
  float*    out    = (float*)d_out;

  hipMemsetAsync(acc, 0, 8 + 4 + 4 * NGRP, stream);  // acc + done + rowcnt
  hipLaunchKernelGGL(fused_kernel, dim3(NGRP, NS), dim3(256), 0, stream,
                     prec, score, pop, sid, lm, ps, xtrow, acc, done, rowcnt, out);
}

// Round 12
// 33.996 us; speedup vs baseline: 3.6579x; 3.6579x over previous
//
#include <hip/hip_runtime.h>

#define NEG_INF (-10000.0f)
#define L_SEQ   100
#define N_COLS  6464      // BS*(L+1)
#define D_      64
#define N_ROWS  6400      // BS*L
#define NS      16        // column splits

// ws byte offsets
#define OFF_PS  0         // float[6400*16] = 409600
#define OFF_XT  409600    // float[6400]    =  25600

typedef __attribute__((ext_vector_type(8))) short short8;
typedef __attribute__((ext_vector_type(4))) float f32x4;
union F8 { short8 v; unsigned short u[8]; unsigned w[4]; };

__device__ __forceinline__ unsigned short f2bf(float f) {  // RTN
  unsigned u = __float_as_uint(f);
  return (unsigned short)((u + 0x7FFFu + ((u >> 16) & 1u)) >> 16);
}
__device__ __forceinline__ unsigned packbf(float lo, float hi) {  // trunc pack
  return (__float_as_uint(hi) & 0xFFFF0000u) | (__float_as_uint(lo) >> 16);
}

// ===== fused_kernel: byte-identical to the round-5 champion (34.29 us) =====
// grid (100, 16), 256 threads = 4 waves; wave owns 16 rows x 1/16 of columns.
// Reads ONLY pristine inputs (L2-replicable). B staged f32->bf16 into swizzled
// LDS shared by the 4 waves; dup-masks via per-block LDS bitsets; target logit
// via one extra MFMA (split 0 only). No max-tracking (logits bounded ~±50).
__global__ __launch_bounds__(256, 4) void fused_kernel(
    const float* __restrict__ prec, const float* __restrict__ score,
    const float* __restrict__ pop, const int* __restrict__ sid,
    const int* __restrict__ lm,
    float* __restrict__ ps, float* __restrict__ xtrow) {
  __shared__ unsigned bs[2 * 3126];        // 2 seq bitsets, 100032 bits each
  __shared__ unsigned short btile[64 * 64];// B supertile, bf16, XOR-swizzled
  __shared__ float mdl[2 * 64];            // mask/pop factor per (seq, col)

  const int tid = threadIdx.x;
  const int split = blockIdx.y;
  const int blkrow = blockIdx.x * 64;
  const int w = tid >> 6, lane = tid & 63;
  const int lr = lane & 15, lk = lane >> 4;
  const int rowbase = blkrow + w * 16;
  const int i0 = blkrow / L_SEQ;
  const int i1 = (blkrow + 63) / L_SEQ;
  const int lim = (i0 + 1) * L_SEQ;
  const int rbase4 = rowbase + lk * 4;     // this lane's 4 acc rows

  // ---- build dup bitsets ----
  for (int x = tid; x < 2 * 3126; x += 256) bs[x] = 0u;
  __syncthreads();
  if (tid < 202) {
    int sel = tid / 101, pos = tid - sel * 101;
    int iq = sel ? i1 : i0;
    int id = sid[iq * 101 + pos];
    atomicOr(&bs[sel * 3126 + (id >> 5)], 1u << (id & 31));
  }

  // ---- A fragments (prec rows, f32->bf16 RTN, once) ----
  const float* prow = prec + (size_t)(rowbase + lr) * D_ + lk * 8;
  F8 fa0, fa1;
  {
    float4 a0 = *(const float4*)(prow);
    float4 a1 = *(const float4*)(prow + 4);
    float4 b0 = *(const float4*)(prow + 32);
    float4 b1 = *(const float4*)(prow + 36);
    fa0.u[0] = f2bf(a0.x); fa0.u[1] = f2bf(a0.y); fa0.u[2] = f2bf(a0.z); fa0.u[3] = f2bf(a0.w);
    fa0.u[4] = f2bf(a1.x); fa0.u[5] = f2bf(a1.y); fa0.u[6] = f2bf(a1.z); fa0.u[7] = f2bf(a1.w);
    fa1.u[0] = f2bf(b0.x); fa1.u[1] = f2bf(b0.y); fa1.u[2] = f2bf(b0.z); fa1.u[3] = f2bf(b0.w);
    fa1.u[4] = f2bf(b1.x); fa1.u[5] = f2bf(b1.y); fa1.u[6] = f2bf(b1.z); fa1.u[7] = f2bf(b1.w);
  }

  float s[4][4];
#pragma unroll
  for (int t4 = 0; t4 < 4; ++t4)
#pragma unroll
    for (int q = 0; q < 4; ++q) s[t4][q] = 0.f;

  // staging registers (tile t+1 in flight during compute of t)
  float4 sv[4];
  int svN = 0, lmvN = 0;

  auto STAGE_ISSUE = [&](int stv) {
    const float* base = score + (size_t)stv * 64 * D_;
#pragma unroll
    for (int j = 0; j < 4; ++j)
      sv[j] = *(const float4*)(base + j * 1024 + tid * 4);
    if (tid < 64) {
      int c = stv * 64 + tid;
      svN = sid[c];
      int i2 = c / 101, p = c - i2 * 101;
      lmvN = (p == L_SEQ) ? 1 : lm[i2 * L_SEQ + p];
    }
  };
  auto STAGE_WRITE = [&]() {
#pragma unroll
    for (int j = 0; j < 4; ++j) {
      int colw = j * 16 + (tid >> 4);
      int byteoff = colw * 128 + ((((tid & 15) * 8)) ^ ((colw & 7) << 4));
      uint2 pk;
      pk.x = packbf(sv[j].x, sv[j].y);
      pk.y = packbf(sv[j].z, sv[j].w);
      *(uint2*)((char*)btile + byteoff) = pk;
    }
    if (tid < 64) {
      float inv = 1.0f / pop[svN];
      unsigned h0 = (bs[svN >> 5] >> (svN & 31)) & 1u;
      unsigned h1 = (bs[3126 + (svN >> 5)] >> (svN & 31)) & 1u;
      mdl[tid] = (lmvN && !h0) ? inv : 0.f;
      mdl[64 + tid] = (lmvN && !h1) ? inv : 0.f;
    }
  };
  auto COMPUTE = [&]() {
    const int sw = (lr & 7) << 4;
    F8 fb0[4], fb1[4];
    float ma[4], mb[4];
#pragma unroll
    for (int t4 = 0; t4 < 4; ++t4) {
      int col = t4 * 16 + lr;
      char* rowp = (char*)btile + col * 128;
      fb0[t4].v = *(const short8*)(rowp + ((lk * 16) ^ sw));
      fb1[t4].v = *(const short8*)(rowp + ((64 + lk * 16) ^ sw));
      ma[t4] = mdl[t4 * 16 + lr];
      mb[t4] = mdl[64 + t4 * 16 + lr];
    }
    f32x4 acc[4];
#pragma unroll
    for (int t4 = 0; t4 < 4; ++t4) {
      f32x4 z = {0.f, 0.f, 0.f, 0.f};
      z = __builtin_amdgcn_mfma_f32_16x16x32_bf16(fa0.v, fb0[t4].v, z, 0, 0, 0);
      z = __builtin_amdgcn_mfma_f32_16x16x32_bf16(fa1.v, fb1[t4].v, z, 0, 0, 0);
      acc[t4] = z;
    }
#pragma unroll
    for (int q = 0; q < 4; ++q) {
      const bool ub = (rbase4 + q) >= lim;
#pragma unroll
      for (int t4 = 0; t4 < 4; ++t4) {
        float mm = ub ? mb[t4] : ma[t4];
        s[t4][q] = fmaf(__expf(acc[t4][q]), mm, s[t4][q]);
      }
    }
  };

  // ---- main loop over this split's supertiles ----
  const int nit = (100 - split) / NS + 1;  // 6 or 7
  int st = split;
  STAGE_ISSUE(st);
  __syncthreads();       // bitsets ready (STAGE_WRITE reads them)
  STAGE_WRITE();
  __syncthreads();       // tile 0 ready
  for (int t = 0; t < nit; ++t) {
    const bool more = (t + 1 < nit);
    if (more) STAGE_ISSUE(st + NS);
    COMPUTE();
    if (more) {
      __syncthreads();   // all waves done reading LDS tile t
      STAGE_WRITE();
      __syncthreads();   // tile t+1 ready
    }
    st += NS;
  }

  // ---- reduce across the 16 col-lanes per row; store partial ----
  float sq[4];
#pragma unroll
  for (int q = 0; q < 4; ++q)
    sq[q] = (s[0][q] + s[1][q]) + (s[2][q] + s[3][q]);
#pragma unroll
  for (int q = 0; q < 4; ++q) {
#pragma unroll
    for (int off = 1; off < 16; off <<= 1)
      sq[q] += __shfl_xor(sq[q], off);
  }
  if (lr == 0) {
#pragma unroll
    for (int q = 0; q < 4; ++q)
      ps[(size_t)(rbase4 + q) * NS + split] = sq[q];
  }

  // ---- target logits: one extra MFMA vs each row's own target column ----
  if (split == 0) {
    int row_l = rowbase + lr;
    int i_l = row_l / L_SEQ, j_l = row_l - i_l * L_SEQ;
    int tgtc = i_l * 101 + j_l + 1;
    int p_l = j_l + 1;
    int vt = (p_l == L_SEQ) ? 1 : lm[i_l * L_SEQ + p_l];
    const float* srp = score + (size_t)tgtc * D_ + lk * 8;
    float4 s0 = *(const float4*)(srp);
    float4 s1 = *(const float4*)(srp + 4);
    float4 s2 = *(const float4*)(srp + 32);
    float4 s3 = *(const float4*)(srp + 36);
    F8 ft0, ft1;
    ft0.w[0] = packbf(s0.x, s0.y); ft0.w[1] = packbf(s0.z, s0.w);
    ft0.w[2] = packbf(s1.x, s1.y); ft0.w[3] = packbf(s1.z, s1.w);
    ft1.w[0] = packbf(s2.x, s2.y); ft1.w[1] = packbf(s2.z, s2.w);
    ft1.w[2] = packbf(s3.x, s3.y); ft1.w[3] = packbf(s3.z, s3.w);
    f32x4 z = {0.f, 0.f, 0.f, 0.f};
    z = __builtin_amdgcn_mfma_f32_16x16x32_bf16(fa0.v, ft0.v, z, 0, 0, 0);
    z = __builtin_amdgcn_mfma_f32_16x16x32_bf16(fa1.v, ft1.v, z, 0, 0, 0);
    int qs = lr - lk * 4;   // diagonal: C[row][col] with row=lk*4+q, col=lr
    if (qs >= 0 && qs < 4) {
      float zd = (qs == 0) ? z[0] : (qs == 1) ? z[1] : (qs == 2) ? z[2] : z[3];
      float xv = zd - __logf(pop[sid[tgtc]]);
      xtrow[row_l] = vt ? xv : NEG_INF;
    }
  }
}

// one block, 1024 threads: per-row sum of 16 partials + target + mean
__global__ __launch_bounds__(1024) void merge_kernel(
    const float* __restrict__ ps, const float* __restrict__ xtrow,
    const int* __restrict__ lm, float* __restrict__ out) {
  float lsum = 0.f, lcnt = 0.f;
  for (int r = threadIdx.x; r < N_ROWS; r += 1024) {
    const float4* pp = (const float4*)(ps + (size_t)r * NS);
    float4 a = pp[0], b = pp[1], c = pp[2], d = pp[3];
    float sv = ((a.x + a.y) + (a.z + a.w)) + ((b.x + b.y) + (b.z + b.w)) +
               ((c.x + c.y) + (c.z + c.w)) + ((d.x + d.y) + (d.z + d.w));
    float x = xtrow[r];
    sv += __expf(x);           // exp(NEG_INF)==0 when target col invalid
    sv = fmaxf(sv, 1e-37f);
    if (lm[r] != 0) { lsum += __logf(sv) - x; lcnt += 1.f; }
  }
#pragma unroll
  for (int off = 1; off < 64; off <<= 1) {
    lsum += __shfl_xor(lsum, off);
    lcnt += __shfl_xor(lcnt, off);
  }
  __shared__ float red[32];
  const int wid = threadIdx.x >> 6, lane = threadIdx.x & 63;
  if (lane == 0) { red[wid] = lsum; red[16 + wid] = lcnt; }
  __syncthreads();
  if (threadIdx.x == 0) {
    float S = 0.f, C = 0.f;
#pragma unroll
    for (int k = 0; k < 16; ++k) { S += red[k]; C += red[16 + k]; }
    out[0] = S / C;
  }
}

extern "C" void kernel_launch(void* const* d_in, const int* in_sizes, int n_in,
                              void* d_out, int out_size, void* d_ws, size_t ws_size,
                              hipStream_t stream) {
  const float* prec  = (const float*)d_in[0];
  const float* score = (const float*)d_in[1];
  const float* pop   = (const float*)d_in[2];
  const int*   sid   = (const int*)d_in[3];
  const int*   lm    = (const int*)d_in[4];

  char* ws = (char*)d_ws;
  float* ps    = (float*)(ws + OFF_PS);
  float* xtrow = (float*)(ws + OFF_XT);
  float* out   = (float*)d_out;

  hipLaunchKernelGGL(fused_kernel, dim3(100, NS), dim3(256), 0, stream,
                     prec, score, pop, sid, lm, ps, xtrow);
  hipLaunchKernelGGL(merge_kernel, dim3(1), dim3(1024), 0, stream,
                     ps, xtrow, lm, out);
}